// Round 6
// baseline (262.407 us; speedup 1.0000x reference)
//
#include <hip/hip_runtime.h>
#include <hip/hip_bf16.h>

#define T_PER_BLK 8
#define EPS_F 1e-5f

typedef __bf16 bf16x8 __attribute__((ext_vector_type(8)));
typedef float f32x4 __attribute__((ext_vector_type(4)));

static __device__ __forceinline__ unsigned int pack_bf16x2(float a, float b) {
    union { float f; unsigned int u; } ca, cb;
    ca.f = a; cb.f = b;
    unsigned int ua = (ca.u + 0x7fffu + ((ca.u >> 16) & 1u)) >> 16;
    unsigned int ub = (cb.u + 0x7fffu + ((cb.u >> 16) & 1u)) >> 16;
    return ua | (ub << 16);
}

static __device__ __forceinline__ float bf_lo(unsigned int u) { return __uint_as_float(u << 16); }
static __device__ __forceinline__ float bf_hi(unsigned int u) { return __uint_as_float(u & 0xffff0000u); }

// ---- setup: wbf[n][k] = bf16(proj_w[n][k] * norm_scale[k]), [48][4096] ----
__global__ void scale_weights(const float* __restrict__ w,
                              const float* __restrict__ ns,
                              unsigned int* __restrict__ wbf)
{
    const int i = (blockIdx.x * 256 + threadIdx.x) * 4;
    const float4 wv = *reinterpret_cast<const float4*>(w + i);
    const float4 nv = *reinterpret_cast<const float4*>(ns + (i & 4095));
    uint2 o;
    o.x = pack_bf16x2(wv.x * nv.x, wv.y * nv.y);
    o.y = pack_bf16x2(wv.z * nv.z, wv.w * nv.w);
    *reinterpret_cast<uint2*>(wbf + (i >> 1)) = o;
}

__global__ __launch_bounds__(512, 4)
void fused_stream_mix(const float* __restrict__ streams,
                      const unsigned short* __restrict__ wbf,   // scaled bf16 weights [48][4096]
                      const float* __restrict__ proj_b,
                      const float* __restrict__ out_scale,
                      float* __restrict__ out)
{
    __shared__ float red[8][3][8][16];   // [kpart][ntile][tokenrow][col] = 12 KB (only LDS)

    const int tid  = threadIdx.x;
    const int wv   = tid >> 6;           // wave == token owner == K-part
    const int lane = tid & 63;
    const size_t tok0 = (size_t)blockIdx.x * T_PER_BLK;

    // ---------- Phase 1: wave wv loads token wv into REGISTERS (bf16), inv RMS ----------
    unsigned int tv[32];                 // 64 bf16 elems: tv[2j],tv[2j+1] = elems j*256+lane*4..+3
    float invr;
    {
        const float* src = streams + (tok0 + wv) * 4096;
        float ssq = 0.f;
        #pragma unroll
        for (int j = 0; j < 16; ++j) {
            float4 v = *reinterpret_cast<const float4*>(src + j * 256 + lane * 4);
            ssq = fmaf(v.x, v.x, ssq); ssq = fmaf(v.y, v.y, ssq);
            ssq = fmaf(v.z, v.z, ssq); ssq = fmaf(v.w, v.w, ssq);
            tv[2 * j]     = pack_bf16x2(v.x, v.y);
            tv[2 * j + 1] = pack_bf16x2(v.z, v.w);
        }
        #pragma unroll
        for (int m = 32; m >= 1; m >>= 1) ssq += __shfl_xor(ssq, m, 64);
        invr = rsqrtf(ssq * (1.f / 4096.f) + EPS_F);
    }
    // CRITICAL barrier: guarantees every wave's phase-1 loads have brought this
    // block's 128 KB of stream lines into L2 before any wave's phase-2 A-reads.
    __syncthreads();

    // ---------- Phase 2: MFMA projection, A re-read from L2, 8-way split-K ----------
    {
        const int arow = lane & 7;                 // token row (dup'd into rows 8..15)
        const int koff = (lane >> 4) * 8;
        const int bcol = lane & 15;
        const int kbase = wv * 512;                // this wave's K eighth

        const float* ap = streams + (tok0 + arow) * 4096 + kbase + koff;
        const unsigned short* wp = wbf + (size_t)bcol * 4096 + kbase + koff;

        f32x4 acc0 = {0.f, 0.f, 0.f, 0.f};
        f32x4 acc1 = acc0, acc2 = acc0;

        #pragma unroll 4
        for (int ks = 0; ks < 16; ++ks) {
            const float4 a0 = *reinterpret_cast<const float4*>(ap + ks * 32);
            const float4 a1 = *reinterpret_cast<const float4*>(ap + ks * 32 + 4);
            bf16x8 a;
            a[0] = (__bf16)a0.x; a[1] = (__bf16)a0.y; a[2] = (__bf16)a0.z; a[3] = (__bf16)a0.w;
            a[4] = (__bf16)a1.x; a[5] = (__bf16)a1.y; a[6] = (__bf16)a1.z; a[7] = (__bf16)a1.w;
            bf16x8 b0 = *reinterpret_cast<const bf16x8*>(wp + ks * 32);
            bf16x8 b1 = *reinterpret_cast<const bf16x8*>(wp + 16 * 4096 + ks * 32);
            bf16x8 b2 = *reinterpret_cast<const bf16x8*>(wp + 32 * 4096 + ks * 32);
            acc0 = __builtin_amdgcn_mfma_f32_16x16x32_bf16(a, b0, acc0, 0, 0, 0);
            acc1 = __builtin_amdgcn_mfma_f32_16x16x32_bf16(a, b1, acc1, 0, 0, 0);
            acc2 = __builtin_amdgcn_mfma_f32_16x16x32_bf16(a, b2, acc2, 0, 0, 0);
        }
        // D layout: col=lane&15, row=(lane>>4)*4+reg; tokens 0..7 live in lanes 0..31
        if (lane < 32) {
            const int col = lane & 15, rg = (lane >> 4) * 4;
            #pragma unroll
            for (int r = 0; r < 4; ++r) {
                red[wv][0][rg + r][col] = acc0[r];
                red[wv][1][rg + r][col] = acc1[r];
                red[wv][2][rg + r][col] = acc2[r];
            }
        }
    }
    __syncthreads();

    // ---------- Phase 3: wave wv builds M for its token (reg-only, tile-at-a-time) ----------
    float Mr[16];
    {
        #define REDUCE_TILE(tile, raw)                                             \
            {                                                                      \
                _Pragma("unroll")                                                  \
                for (int c4 = 0; c4 < 4; ++c4) {                                   \
                    f32x4 s = {0.f, 0.f, 0.f, 0.f};                                \
                    _Pragma("unroll")                                              \
                    for (int kp = 0; kp < 8; ++kp)                                 \
                        s += *reinterpret_cast<const f32x4*>(&red[kp][tile][wv][c4 * 4]); \
                    const float4 pb = *reinterpret_cast<const float4*>(&proj_b[tile * 16 + c4 * 4]); \
                    raw[c4*4 + 0] = s[0] * invr + pb.x;                            \
                    raw[c4*4 + 1] = s[1] * invr + pb.y;                            \
                    raw[c4*4 + 2] = s[2] * invr + pb.z;                            \
                    raw[c4*4 + 3] = s[3] * invr + pb.w;                            \
                }                                                                  \
            }

        // H_pre row-softmax -> c[j] = 0.25 * column sums
        float c[4] = {0.f, 0.f, 0.f, 0.f};
        {
            float raw[16];
            REDUCE_TILE(0, raw)
            #pragma unroll
            for (int i = 0; i < 4; ++i) {
                const float a0 = raw[i*4+0], a1 = raw[i*4+1], a2 = raw[i*4+2], a3 = raw[i*4+3];
                const float m = fmaxf(fmaxf(a0, a1), fmaxf(a2, a3));
                const float e0 = expf(a0 - m), e1 = expf(a1 - m);
                const float e2 = expf(a2 - m), e3 = expf(a3 - m);
                const float inv = 1.f / (e0 + e1 + e2 + e3);
                c[0] = fmaf(e0, inv, c[0]); c[1] = fmaf(e1, inv, c[1]);
                c[2] = fmaf(e2, inv, c[2]); c[3] = fmaf(e3, inv, c[3]);
            }
            c[0] *= 0.25f; c[1] *= 0.25f; c[2] *= 0.25f; c[3] *= 0.25f;
        }

        // H_post column-softmax -> rs[i] = row sums
        float rs[4] = {0.f, 0.f, 0.f, 0.f};
        {
            float raw[16];
            REDUCE_TILE(1, raw)
            #pragma unroll
            for (int j = 0; j < 4; ++j) {
                const float b0 = raw[j], b1 = raw[4+j], b2 = raw[8+j], b3 = raw[12+j];
                const float m = fmaxf(fmaxf(b0, b1), fmaxf(b2, b3));
                const float e0 = expf(b0 - m), e1 = expf(b1 - m);
                const float e2 = expf(b2 - m), e3 = expf(b3 - m);
                const float inv = 1.f / (e0 + e1 + e2 + e3);
                rs[0] = fmaf(e0, inv, rs[0]); rs[1] = fmaf(e1, inv, rs[1]);
                rs[2] = fmaf(e2, inv, rs[2]); rs[3] = fmaf(e3, inv, rs[3]);
            }
        }

        // Cayley iterative
        float W[16], Y[16];
        {
            float raw[16];
            REDUCE_TILE(2, raw)
            #pragma unroll
            for (int i = 0; i < 4; ++i)
                #pragma unroll
                for (int j = 0; j < 4; ++j)
                    W[i*4+j] = raw[i*4+j] - raw[j*4+i];
        }
        #pragma unroll
        for (int i = 0; i < 16; ++i) Y[i] = 0.1f * W[i];
        Y[0] += 1.f; Y[5] += 1.f; Y[10] += 1.f; Y[15] += 1.f;
        #pragma unroll
        for (int it = 0; it < 2; ++it) {
            float T1[16];
            #pragma unroll
            for (int i = 0; i < 16; ++i) T1[i] = Y[i];
            T1[0] += 1.f; T1[5] += 1.f; T1[10] += 1.f; T1[15] += 1.f;
            float Yn[16];
            #pragma unroll
            for (int i = 0; i < 4; ++i)
                #pragma unroll
                for (int j = 0; j < 4; ++j) {
                    float s = W[i*4+0] * T1[0*4+j];
                    s = fmaf(W[i*4+1], T1[1*4+j], s);
                    s = fmaf(W[i*4+2], T1[2*4+j], s);
                    s = fmaf(W[i*4+3], T1[3*4+j], s);
                    Yn[i*4+j] = ((i == j) ? 1.f : 0.f) + 0.05f * s;
                }
            #pragma unroll
            for (int i = 0; i < 16; ++i) Y[i] = Yn[i];
        }

        const float os = out_scale[0];
        #pragma unroll
        for (int i = 0; i < 4; ++i)
            #pragma unroll
            for (int j = 0; j < 4; ++j)
                Mr[i*4+j] = Y[i*4+j] + os * rs[i] * c[j];
        #undef REDUCE_TILE
    }

    // ---------- Phase 4: out[token wv] = M @ x, from registers, float4 stores ----------
    {
        float* dst = out + (tok0 + wv) * 4096;
        #pragma unroll
        for (int jj = 0; jj < 4; ++jj) {             // column chunk within each d-row
            float x[4][4];
            #pragma unroll
            for (int r = 0; r < 4; ++r) {
                const unsigned int u0 = tv[(r * 4 + jj) * 2];
                const unsigned int u1 = tv[(r * 4 + jj) * 2 + 1];
                x[r][0] = bf_lo(u0); x[r][1] = bf_hi(u0);
                x[r][2] = bf_lo(u1); x[r][3] = bf_hi(u1);
            }
            #pragma unroll
            for (int i = 0; i < 4; ++i) {
                float4 o;
                o.x = Mr[i*4+0]*x[0][0]; o.y = Mr[i*4+0]*x[0][1];
                o.z = Mr[i*4+0]*x[0][2]; o.w = Mr[i*4+0]*x[0][3];
                #pragma unroll
                for (int r = 1; r < 4; ++r) {
                    o.x = fmaf(Mr[i*4+r], x[r][0], o.x);
                    o.y = fmaf(Mr[i*4+r], x[r][1], o.y);
                    o.z = fmaf(Mr[i*4+r], x[r][2], o.z);
                    o.w = fmaf(Mr[i*4+r], x[r][3], o.w);
                }
                *reinterpret_cast<float4*>(dst + i * 1024 + jj * 256 + lane * 4) = o;
            }
        }
    }
}

extern "C" void kernel_launch(void* const* d_in, const int* in_sizes, int n_in,
                              void* d_out, int out_size, void* d_ws, size_t ws_size,
                              hipStream_t stream) {
    const float* streams    = (const float*)d_in[0];
    const float* norm_scale = (const float*)d_in[1];
    const float* proj_w     = (const float*)d_in[2];
    const float* proj_b     = (const float*)d_in[3];
    const float* out_scale  = (const float*)d_in[4];
    float* outp = (float*)d_out;

    unsigned int* wbf = (unsigned int*)d_ws;       // 48*4096 bf16 = 393216 B

    scale_weights<<<dim3(192), 256, 0, stream>>>(proj_w, norm_scale, wbf);

    const int n_tok = in_sizes[0] / 4096;          // B*S = 16384
    dim3 grid(n_tok / T_PER_BLK);                  // 2048 blocks
    fused_stream_mix<<<grid, 512, 0, stream>>>(streams,
                                               (const unsigned short*)wbf,
                                               proj_b, out_scale, outp);
}

// Round 7
// 258.538 us; speedup vs baseline: 1.0150x; 1.0150x over previous
//
#include <hip/hip_runtime.h>
#include <hip/hip_bf16.h>

#define T_PER_BLK 8
#define EPS_F 1e-5f

typedef __bf16 bf16x8 __attribute__((ext_vector_type(8)));
typedef float f32x4 __attribute__((ext_vector_type(4)));

static __device__ __forceinline__ unsigned int pack_bf16x2(float a, float b) {
    union { float f; unsigned int u; } ca, cb;
    ca.f = a; cb.f = b;
    unsigned int ua = (ca.u + 0x7fffu + ((ca.u >> 16) & 1u)) >> 16;
    unsigned int ub = (cb.u + 0x7fffu + ((cb.u >> 16) & 1u)) >> 16;
    return ua | (ub << 16);
}

static __device__ __forceinline__ float bf_lo(unsigned int u) { return __uint_as_float(u << 16); }
static __device__ __forceinline__ float bf_hi(unsigned int u) { return __uint_as_float(u & 0xffff0000u); }

// ---- setup: wbf[n][k] = bf16(proj_w[n][k] * norm_scale[k]), [48][4096] ----
__global__ void scale_weights(const float* __restrict__ w,
                              const float* __restrict__ ns,
                              unsigned int* __restrict__ wbf)
{
    const int i = (blockIdx.x * 256 + threadIdx.x) * 4;
    const float4 wv = *reinterpret_cast<const float4*>(w + i);
    const float4 nv = *reinterpret_cast<const float4*>(ns + (i & 4095));
    uint2 o;
    o.x = pack_bf16x2(wv.x * nv.x, wv.y * nv.y);
    o.y = pack_bf16x2(wv.z * nv.z, wv.w * nv.w);
    *reinterpret_cast<uint2*>(wbf + (i >> 1)) = o;
}

// NOTE: second launch_bounds arg = 2 (NOT 4): with 8-wave blocks, 4 forced an
// 8-waves/SIMD VGPR budget (64 regs) and tv[32] spilled to scratch -> +280 MB
// of HBM traffic (R5/R6 regression). 2 -> 128-VGPR cap, zero spill.
__global__ __launch_bounds__(512, 2)
void fused_stream_mix(const float* __restrict__ streams,
                      const unsigned short* __restrict__ wbf,   // scaled bf16 weights [48][4096]
                      const float* __restrict__ proj_b,
                      const float* __restrict__ out_scale,
                      float* __restrict__ out)
{
    __shared__ float red[8][3][8][16];   // [kpart][ntile][tokenrow][col] = 12 KB (only LDS)

    const int tid  = threadIdx.x;
    const int wv   = tid >> 6;           // wave == token owner == K-part
    const int lane = tid & 63;
    const size_t tok0 = (size_t)blockIdx.x * T_PER_BLK;

    // ---------- Phase 1: wave wv loads token wv into REGISTERS (bf16), inv RMS ----------
    unsigned int tv[32];                 // 64 bf16 elems: tv[2j],tv[2j+1] = elems j*256+lane*4..+3
    float invr;
    {
        const float* src = streams + (tok0 + wv) * 4096;
        float ssq = 0.f;
        #pragma unroll
        for (int j = 0; j < 16; ++j) {
            float4 v = *reinterpret_cast<const float4*>(src + j * 256 + lane * 4);
            ssq = fmaf(v.x, v.x, ssq); ssq = fmaf(v.y, v.y, ssq);
            ssq = fmaf(v.z, v.z, ssq); ssq = fmaf(v.w, v.w, ssq);
            tv[2 * j]     = pack_bf16x2(v.x, v.y);
            tv[2 * j + 1] = pack_bf16x2(v.z, v.w);
        }
        #pragma unroll
        for (int m = 32; m >= 1; m >>= 1) ssq += __shfl_xor(ssq, m, 64);
        invr = rsqrtf(ssq * (1.f / 4096.f) + EPS_F);
    }
    // Barrier: all stream lines of this block are in L2 before phase-2 A re-reads.
    __syncthreads();

    // ---------- Phase 2: MFMA projection, A re-read from L2, 8-way split-K ----------
    {
        const int arow = lane & 7;                 // token row (dup'd into rows 8..15)
        const int koff = (lane >> 4) * 8;
        const int bcol = lane & 15;
        const int kbase = wv * 512;                // this wave's K eighth

        const float* ap = streams + (tok0 + arow) * 4096 + kbase + koff;
        const unsigned short* wp = wbf + (size_t)bcol * 4096 + kbase + koff;

        f32x4 acc0 = {0.f, 0.f, 0.f, 0.f};
        f32x4 acc1 = acc0, acc2 = acc0;

        #pragma unroll 8
        for (int ks = 0; ks < 16; ++ks) {
            const float4 a0 = *reinterpret_cast<const float4*>(ap + ks * 32);
            const float4 a1 = *reinterpret_cast<const float4*>(ap + ks * 32 + 4);
            bf16x8 a;
            a[0] = (__bf16)a0.x; a[1] = (__bf16)a0.y; a[2] = (__bf16)a0.z; a[3] = (__bf16)a0.w;
            a[4] = (__bf16)a1.x; a[5] = (__bf16)a1.y; a[6] = (__bf16)a1.z; a[7] = (__bf16)a1.w;
            bf16x8 b0 = *reinterpret_cast<const bf16x8*>(wp + ks * 32);
            bf16x8 b1 = *reinterpret_cast<const bf16x8*>(wp + 16 * 4096 + ks * 32);
            bf16x8 b2 = *reinterpret_cast<const bf16x8*>(wp + 32 * 4096 + ks * 32);
            acc0 = __builtin_amdgcn_mfma_f32_16x16x32_bf16(a, b0, acc0, 0, 0, 0);
            acc1 = __builtin_amdgcn_mfma_f32_16x16x32_bf16(a, b1, acc1, 0, 0, 0);
            acc2 = __builtin_amdgcn_mfma_f32_16x16x32_bf16(a, b2, acc2, 0, 0, 0);
        }
        // D layout: col=lane&15, row=(lane>>4)*4+reg; tokens 0..7 live in lanes 0..31
        if (lane < 32) {
            const int col = lane & 15, rg = (lane >> 4) * 4;
            #pragma unroll
            for (int r = 0; r < 4; ++r) {
                red[wv][0][rg + r][col] = acc0[r];
                red[wv][1][rg + r][col] = acc1[r];
                red[wv][2][rg + r][col] = acc2[r];
            }
        }
    }
    __syncthreads();

    // ---------- Phase 3: wave wv builds M for its token (reg-only, tile-at-a-time) ----------
    float Mr[16];
    {
        #define REDUCE_TILE(tile, raw)                                             \
            {                                                                      \
                _Pragma("unroll")                                                  \
                for (int c4 = 0; c4 < 4; ++c4) {                                   \
                    f32x4 s = {0.f, 0.f, 0.f, 0.f};                                \
                    _Pragma("unroll")                                              \
                    for (int kp = 0; kp < 8; ++kp)                                 \
                        s += *reinterpret_cast<const f32x4*>(&red[kp][tile][wv][c4 * 4]); \
                    const float4 pb = *reinterpret_cast<const float4*>(&proj_b[tile * 16 + c4 * 4]); \
                    raw[c4*4 + 0] = s[0] * invr + pb.x;                            \
                    raw[c4*4 + 1] = s[1] * invr + pb.y;                            \
                    raw[c4*4 + 2] = s[2] * invr + pb.z;                            \
                    raw[c4*4 + 3] = s[3] * invr + pb.w;                            \
                }                                                                  \
            }

        // H_pre row-softmax -> c[j] = 0.25 * column sums
        float c[4] = {0.f, 0.f, 0.f, 0.f};
        {
            float raw[16];
            REDUCE_TILE(0, raw)
            #pragma unroll
            for (int i = 0; i < 4; ++i) {
                const float a0 = raw[i*4+0], a1 = raw[i*4+1], a2 = raw[i*4+2], a3 = raw[i*4+3];
                const float m = fmaxf(fmaxf(a0, a1), fmaxf(a2, a3));
                const float e0 = expf(a0 - m), e1 = expf(a1 - m);
                const float e2 = expf(a2 - m), e3 = expf(a3 - m);
                const float inv = 1.f / (e0 + e1 + e2 + e3);
                c[0] = fmaf(e0, inv, c[0]); c[1] = fmaf(e1, inv, c[1]);
                c[2] = fmaf(e2, inv, c[2]); c[3] = fmaf(e3, inv, c[3]);
            }
            c[0] *= 0.25f; c[1] *= 0.25f; c[2] *= 0.25f; c[3] *= 0.25f;
        }

        // H_post column-softmax -> rs[i] = row sums
        float rs[4] = {0.f, 0.f, 0.f, 0.f};
        {
            float raw[16];
            REDUCE_TILE(1, raw)
            #pragma unroll
            for (int j = 0; j < 4; ++j) {
                const float b0 = raw[j], b1 = raw[4+j], b2 = raw[8+j], b3 = raw[12+j];
                const float m = fmaxf(fmaxf(b0, b1), fmaxf(b2, b3));
                const float e0 = expf(b0 - m), e1 = expf(b1 - m);
                const float e2 = expf(b2 - m), e3 = expf(b3 - m);
                const float inv = 1.f / (e0 + e1 + e2 + e3);
                rs[0] = fmaf(e0, inv, rs[0]); rs[1] = fmaf(e1, inv, rs[1]);
                rs[2] = fmaf(e2, inv, rs[2]); rs[3] = fmaf(e3, inv, rs[3]);
            }
        }

        // Cayley iterative
        float W[16], Y[16];
        {
            float raw[16];
            REDUCE_TILE(2, raw)
            #pragma unroll
            for (int i = 0; i < 4; ++i)
                #pragma unroll
                for (int j = 0; j < 4; ++j)
                    W[i*4+j] = raw[i*4+j] - raw[j*4+i];
        }
        #pragma unroll
        for (int i = 0; i < 16; ++i) Y[i] = 0.1f * W[i];
        Y[0] += 1.f; Y[5] += 1.f; Y[10] += 1.f; Y[15] += 1.f;
        #pragma unroll
        for (int it = 0; it < 2; ++it) {
            float T1[16];
            #pragma unroll
            for (int i = 0; i < 16; ++i) T1[i] = Y[i];
            T1[0] += 1.f; T1[5] += 1.f; T1[10] += 1.f; T1[15] += 1.f;
            float Yn[16];
            #pragma unroll
            for (int i = 0; i < 4; ++i)
                #pragma unroll
                for (int j = 0; j < 4; ++j) {
                    float s = W[i*4+0] * T1[0*4+j];
                    s = fmaf(W[i*4+1], T1[1*4+j], s);
                    s = fmaf(W[i*4+2], T1[2*4+j], s);
                    s = fmaf(W[i*4+3], T1[3*4+j], s);
                    Yn[i*4+j] = ((i == j) ? 1.f : 0.f) + 0.05f * s;
                }
            #pragma unroll
            for (int i = 0; i < 16; ++i) Y[i] = Yn[i];
        }

        const float os = out_scale[0];
        #pragma unroll
        for (int i = 0; i < 4; ++i)
            #pragma unroll
            for (int j = 0; j < 4; ++j)
                Mr[i*4+j] = Y[i*4+j] + os * rs[i] * c[j];
        #undef REDUCE_TILE
    }

    // ---------- Phase 4: out[token wv] = M @ x, from registers, float4 stores ----------
    {
        float* dst = out + (tok0 + wv) * 4096;
        #pragma unroll
        for (int jj = 0; jj < 4; ++jj) {             // column chunk within each d-row
            float x[4][4];
            #pragma unroll
            for (int r = 0; r < 4; ++r) {
                const unsigned int u0 = tv[(r * 4 + jj) * 2];
                const unsigned int u1 = tv[(r * 4 + jj) * 2 + 1];
                x[r][0] = bf_lo(u0); x[r][1] = bf_hi(u0);
                x[r][2] = bf_lo(u1); x[r][3] = bf_hi(u1);
            }
            #pragma unroll
            for (int i = 0; i < 4; ++i) {
                float4 o;
                o.x = Mr[i*4+0]*x[0][0]; o.y = Mr[i*4+0]*x[0][1];
                o.z = Mr[i*4+0]*x[0][2]; o.w = Mr[i*4+0]*x[0][3];
                #pragma unroll
                for (int r = 1; r < 4; ++r) {
                    o.x = fmaf(Mr[i*4+r], x[r][0], o.x);
                    o.y = fmaf(Mr[i*4+r], x[r][1], o.y);
                    o.z = fmaf(Mr[i*4+r], x[r][2], o.z);
                    o.w = fmaf(Mr[i*4+r], x[r][3], o.w);
                }
                *reinterpret_cast<float4*>(dst + i * 1024 + jj * 256 + lane * 4) = o;
            }
        }
    }
}

extern "C" void kernel_launch(void* const* d_in, const int* in_sizes, int n_in,
                              void* d_out, int out_size, void* d_ws, size_t ws_size,
                              hipStream_t stream) {
    const float* streams    = (const float*)d_in[0];
    const float* norm_scale = (const float*)d_in[1];
    const float* proj_w     = (const float*)d_in[2];
    const float* proj_b     = (const float*)d_in[3];
    const float* out_scale  = (const float*)d_in[4];
    float* outp = (float*)d_out;

    unsigned int* wbf = (unsigned int*)d_ws;       // 48*4096 bf16 = 393216 B

    scale_weights<<<dim3(192), 256, 0, stream>>>(proj_w, norm_scale, wbf);

    const int n_tok = in_sizes[0] / 4096;          // B*S = 16384
    dim3 grid(n_tok / T_PER_BLK);                  // 2048 blocks
    fused_stream_mix<<<grid, 512, 0, stream>>>(streams,
                                               (const unsigned short*)wbf,
                                               proj_b, out_scale, outp);
}

// Round 8
// 246.858 us; speedup vs baseline: 1.0630x; 1.0473x over previous
//
#include <hip/hip_runtime.h>
#include <hip/hip_bf16.h>

#define EPS_F 1e-5f

typedef __bf16 bf16x8 __attribute__((ext_vector_type(8)));
typedef float f32x4 __attribute__((ext_vector_type(4)));

static __device__ __forceinline__ unsigned int pack_bf16x2(float a, float b) {
    union { float f; unsigned int u; } ca, cb;
    ca.f = a; cb.f = b;
    unsigned int ua = (ca.u + 0x7fffu + ((ca.u >> 16) & 1u)) >> 16;
    unsigned int ub = (cb.u + 0x7fffu + ((cb.u >> 16) & 1u)) >> 16;
    return ua | (ub << 16);
}

// ---- setup: wbf[n][k] = bf16(proj_w[n][k] * norm_scale[k]), [48][4096] ----
__global__ void scale_weights(const float* __restrict__ w,
                              const float* __restrict__ ns,
                              unsigned int* __restrict__ wbf)
{
    const int i = (blockIdx.x * 256 + threadIdx.x) * 4;
    const float4 wv = *reinterpret_cast<const float4*>(w + i);
    const float4 nv = *reinterpret_cast<const float4*>(ns + (i & 4095));
    uint2 o;
    o.x = pack_bf16x2(wv.x * nv.x, wv.y * nv.y);
    o.y = pack_bf16x2(wv.z * nv.z, wv.w * nv.w);
    *reinterpret_cast<uint2*>(wbf + (i >> 1)) = o;
}

// ================= Kernel A: compute per-token 4x4 combine matrix M =========
// Reads streams exactly ONCE (as MFMA A-fragments, direct from global).
// ssq piggybacked on the A-loads. One barrier. Writes M[16384][16] (1 MB).
__global__ __launch_bounds__(512)
void compute_M(const float* __restrict__ streams,
               const unsigned short* __restrict__ wbf,   // scaled bf16 W [48][4096]
               const float* __restrict__ proj_b,
               const float* __restrict__ out_scale,
               float* __restrict__ Mout)
{
    __shared__ float red[8][3][8][16];   // [kpart][ntile][tokenrow][col] = 12 KB
    __shared__ float ssq_red[8][8];      // [kpart][token]

    const int tid  = threadIdx.x;
    const int wv   = tid >> 6;           // wave == token owner == K-part
    const int lane = tid & 63;
    const size_t tok0 = (size_t)blockIdx.x * 8;

    // ---------- MFMA projection, A direct-from-global (single read), 8-way split-K ----------
    {
        const int arow = lane & 7;                 // token row (dup'd into rows 8..15)
        const int koff = (lane >> 4) * 8;
        const int bcol = lane & 15;
        const int kbase = wv * 512;                // this wave's K eighth

        const float* ap = streams + (tok0 + arow) * 4096 + kbase + koff;
        const unsigned short* wp = wbf + (size_t)bcol * 4096 + kbase + koff;

        f32x4 acc0 = {0.f, 0.f, 0.f, 0.f};
        f32x4 acc1 = acc0, acc2 = acc0;
        float ssq = 0.f;

        #pragma unroll 8
        for (int ks = 0; ks < 16; ++ks) {
            const float4 a0 = *reinterpret_cast<const float4*>(ap + ks * 32);
            const float4 a1 = *reinterpret_cast<const float4*>(ap + ks * 32 + 4);
            ssq = fmaf(a0.x, a0.x, ssq); ssq = fmaf(a0.y, a0.y, ssq);
            ssq = fmaf(a0.z, a0.z, ssq); ssq = fmaf(a0.w, a0.w, ssq);
            ssq = fmaf(a1.x, a1.x, ssq); ssq = fmaf(a1.y, a1.y, ssq);
            ssq = fmaf(a1.z, a1.z, ssq); ssq = fmaf(a1.w, a1.w, ssq);
            bf16x8 a;
            a[0] = (__bf16)a0.x; a[1] = (__bf16)a0.y; a[2] = (__bf16)a0.z; a[3] = (__bf16)a0.w;
            a[4] = (__bf16)a1.x; a[5] = (__bf16)a1.y; a[6] = (__bf16)a1.z; a[7] = (__bf16)a1.w;
            bf16x8 b0 = *reinterpret_cast<const bf16x8*>(wp + ks * 32);
            bf16x8 b1 = *reinterpret_cast<const bf16x8*>(wp + 16 * 4096 + ks * 32);
            bf16x8 b2 = *reinterpret_cast<const bf16x8*>(wp + 32 * 4096 + ks * 32);
            acc0 = __builtin_amdgcn_mfma_f32_16x16x32_bf16(a, b0, acc0, 0, 0, 0);
            acc1 = __builtin_amdgcn_mfma_f32_16x16x32_bf16(a, b1, acc1, 0, 0, 0);
            acc2 = __builtin_amdgcn_mfma_f32_16x16x32_bf16(a, b2, acc2, 0, 0, 0);
        }
        // ssq: lanes {l, l^16, l^32, l^48} cover koffs {0,8,16,24} exactly once.
        ssq += __shfl_xor(ssq, 16, 64);
        ssq += __shfl_xor(ssq, 32, 64);
        if (lane < 8) ssq_red[wv][lane] = ssq;   // lane t holds token t's K-eighth ssq

        // D layout: col=lane&15, row=(lane>>4)*4+reg; tokens 0..7 live in lanes 0..31
        if (lane < 32) {
            const int col = lane & 15, rg = (lane >> 4) * 4;
            #pragma unroll
            for (int r = 0; r < 4; ++r) {
                red[wv][0][rg + r][col] = acc0[r];
                red[wv][1][rg + r][col] = acc1[r];
                red[wv][2][rg + r][col] = acc2[r];
            }
        }
    }
    __syncthreads();   // the only barrier

    // ---------- wave wv builds M for its token (reg-only, redundant per lane) ----------
    float Mr[16];
    {
        float st = 0.f;
        #pragma unroll
        for (int kp = 0; kp < 8; ++kp) st += ssq_red[kp][wv];
        const float invr = rsqrtf(st * (1.f / 4096.f) + EPS_F);

        #define REDUCE_TILE(tile, raw)                                             \
            {                                                                      \
                _Pragma("unroll")                                                  \
                for (int c4 = 0; c4 < 4; ++c4) {                                   \
                    f32x4 s = {0.f, 0.f, 0.f, 0.f};                                \
                    _Pragma("unroll")                                              \
                    for (int kp = 0; kp < 8; ++kp)                                 \
                        s += *reinterpret_cast<const f32x4*>(&red[kp][tile][wv][c4 * 4]); \
                    const float4 pb = *reinterpret_cast<const float4*>(&proj_b[tile * 16 + c4 * 4]); \
                    raw[c4*4 + 0] = s[0] * invr + pb.x;                            \
                    raw[c4*4 + 1] = s[1] * invr + pb.y;                            \
                    raw[c4*4 + 2] = s[2] * invr + pb.z;                            \
                    raw[c4*4 + 3] = s[3] * invr + pb.w;                            \
                }                                                                  \
            }

        // H_pre row-softmax -> c[j] = 0.25 * column sums
        float c[4] = {0.f, 0.f, 0.f, 0.f};
        {
            float raw[16];
            REDUCE_TILE(0, raw)
            #pragma unroll
            for (int i = 0; i < 4; ++i) {
                const float a0 = raw[i*4+0], a1 = raw[i*4+1], a2 = raw[i*4+2], a3 = raw[i*4+3];
                const float m = fmaxf(fmaxf(a0, a1), fmaxf(a2, a3));
                const float e0 = expf(a0 - m), e1 = expf(a1 - m);
                const float e2 = expf(a2 - m), e3 = expf(a3 - m);
                const float inv = 1.f / (e0 + e1 + e2 + e3);
                c[0] = fmaf(e0, inv, c[0]); c[1] = fmaf(e1, inv, c[1]);
                c[2] = fmaf(e2, inv, c[2]); c[3] = fmaf(e3, inv, c[3]);
            }
            c[0] *= 0.25f; c[1] *= 0.25f; c[2] *= 0.25f; c[3] *= 0.25f;
        }

        // H_post column-softmax -> rs[i] = row sums
        float rs[4] = {0.f, 0.f, 0.f, 0.f};
        {
            float raw[16];
            REDUCE_TILE(1, raw)
            #pragma unroll
            for (int j = 0; j < 4; ++j) {
                const float b0 = raw[j], b1 = raw[4+j], b2 = raw[8+j], b3 = raw[12+j];
                const float m = fmaxf(fmaxf(b0, b1), fmaxf(b2, b3));
                const float e0 = expf(b0 - m), e1 = expf(b1 - m);
                const float e2 = expf(b2 - m), e3 = expf(b3 - m);
                const float inv = 1.f / (e0 + e1 + e2 + e3);
                rs[0] = fmaf(e0, inv, rs[0]); rs[1] = fmaf(e1, inv, rs[1]);
                rs[2] = fmaf(e2, inv, rs[2]); rs[3] = fmaf(e3, inv, rs[3]);
            }
        }

        // Cayley iterative
        float W[16], Y[16];
        {
            float raw[16];
            REDUCE_TILE(2, raw)
            #pragma unroll
            for (int i = 0; i < 4; ++i)
                #pragma unroll
                for (int j = 0; j < 4; ++j)
                    W[i*4+j] = raw[i*4+j] - raw[j*4+i];
        }
        #pragma unroll
        for (int i = 0; i < 16; ++i) Y[i] = 0.1f * W[i];
        Y[0] += 1.f; Y[5] += 1.f; Y[10] += 1.f; Y[15] += 1.f;
        #pragma unroll
        for (int it = 0; it < 2; ++it) {
            float T1[16];
            #pragma unroll
            for (int i = 0; i < 16; ++i) T1[i] = Y[i];
            T1[0] += 1.f; T1[5] += 1.f; T1[10] += 1.f; T1[15] += 1.f;
            float Yn[16];
            #pragma unroll
            for (int i = 0; i < 4; ++i)
                #pragma unroll
                for (int j = 0; j < 4; ++j) {
                    float s = W[i*4+0] * T1[0*4+j];
                    s = fmaf(W[i*4+1], T1[1*4+j], s);
                    s = fmaf(W[i*4+2], T1[2*4+j], s);
                    s = fmaf(W[i*4+3], T1[3*4+j], s);
                    Yn[i*4+j] = ((i == j) ? 1.f : 0.f) + 0.05f * s;
                }
            #pragma unroll
            for (int i = 0; i < 16; ++i) Y[i] = Yn[i];
        }

        const float os = out_scale[0];
        #pragma unroll
        for (int i = 0; i < 4; ++i)
            #pragma unroll
            for (int j = 0; j < 4; ++j)
                Mr[i*4+j] = Y[i*4+j] + os * rs[i] * c[j];
        #undef REDUCE_TILE
    }

    if (lane == 0) {
        float* mp = Mout + (tok0 + wv) * 16;
        *reinterpret_cast<float4*>(mp +  0) = make_float4(Mr[0],  Mr[1],  Mr[2],  Mr[3]);
        *reinterpret_cast<float4*>(mp +  4) = make_float4(Mr[4],  Mr[5],  Mr[6],  Mr[7]);
        *reinterpret_cast<float4*>(mp +  8) = make_float4(Mr[8],  Mr[9],  Mr[10], Mr[11]);
        *reinterpret_cast<float4*>(mp + 12) = make_float4(Mr[12], Mr[13], Mr[14], Mr[15]);
    }
}

// ================= Kernel B: out[t] = M[t] @ streams[t] — pure streaming ====
static __device__ __forceinline__ float4 mix4(float4 m, float4 x0, float4 x1,
                                              float4 x2, float4 x3) {
    float4 o;
    o.x = fmaf(m.w, x3.x, fmaf(m.z, x2.x, fmaf(m.y, x1.x, m.x * x0.x)));
    o.y = fmaf(m.w, x3.y, fmaf(m.z, x2.y, fmaf(m.y, x1.y, m.x * x0.y)));
    o.z = fmaf(m.w, x3.z, fmaf(m.z, x2.z, fmaf(m.y, x1.z, m.x * x0.z)));
    o.w = fmaf(m.w, x3.w, fmaf(m.z, x2.w, fmaf(m.y, x1.w, m.x * x0.w)));
    return o;
}

__global__ __launch_bounds__(256)
void apply_M(const float* __restrict__ streams,
             const float* __restrict__ Mfull,
             float* __restrict__ out)
{
    const size_t t = blockIdx.x;           // token
    const int c = threadIdx.x * 4;         // column quad

    const float4* mp = reinterpret_cast<const float4*>(Mfull + t * 16);
    const float4 m0 = mp[0], m1 = mp[1], m2 = mp[2], m3 = mp[3];

    const float* src = streams + t * 4096;
    float* dst = out + t * 4096;

    const float4 x0 = *reinterpret_cast<const float4*>(src + c);
    const float4 x1 = *reinterpret_cast<const float4*>(src + 1024 + c);
    const float4 x2 = *reinterpret_cast<const float4*>(src + 2048 + c);
    const float4 x3 = *reinterpret_cast<const float4*>(src + 3072 + c);

    *reinterpret_cast<float4*>(dst +        c) = mix4(m0, x0, x1, x2, x3);
    *reinterpret_cast<float4*>(dst + 1024 + c) = mix4(m1, x0, x1, x2, x3);
    *reinterpret_cast<float4*>(dst + 2048 + c) = mix4(m2, x0, x1, x2, x3);
    *reinterpret_cast<float4*>(dst + 3072 + c) = mix4(m3, x0, x1, x2, x3);
}

extern "C" void kernel_launch(void* const* d_in, const int* in_sizes, int n_in,
                              void* d_out, int out_size, void* d_ws, size_t ws_size,
                              hipStream_t stream) {
    const float* streams    = (const float*)d_in[0];
    const float* norm_scale = (const float*)d_in[1];
    const float* proj_w     = (const float*)d_in[2];
    const float* proj_b     = (const float*)d_in[3];
    const float* out_scale  = (const float*)d_in[4];
    float* outp = (float*)d_out;

    unsigned int* wbf = (unsigned int*)d_ws;                    // 393216 B
    float* Mfull = (float*)((char*)d_ws + 393216);              // 16384*16*4 = 1 MB

    scale_weights<<<dim3(192), 256, 0, stream>>>(proj_w, norm_scale, wbf);

    const int n_tok = in_sizes[0] / 4096;          // B*S = 16384
    compute_M<<<dim3(n_tok / 8), 512, 0, stream>>>(streams,
                                                   (const unsigned short*)wbf,
                                                   proj_b, out_scale, Mfull);
    apply_M<<<dim3(n_tok), 256, 0, stream>>>(streams, Mfull, outp);
}

// Round 9
// 190.927 us; speedup vs baseline: 1.3744x; 1.2929x over previous
//
#include <hip/hip_runtime.h>
#include <hip/hip_bf16.h>

#define EPS_F 1e-5f

typedef __bf16 bf16x8 __attribute__((ext_vector_type(8)));
typedef float f32x4 __attribute__((ext_vector_type(4)));

static __device__ __forceinline__ unsigned int pack_bf16x2(float a, float b) {
    union { float f; unsigned int u; } ca, cb;
    ca.f = a; cb.f = b;
    unsigned int ua = (ca.u + 0x7fffu + ((ca.u >> 16) & 1u)) >> 16;
    unsigned int ub = (cb.u + 0x7fffu + ((cb.u >> 16) & 1u)) >> 16;
    return ua | (ub << 16);
}

// ---- setup: wbf[n][k] = bf16(proj_w[n][k] * norm_scale[k]), [48][4096] ----
__global__ void scale_weights(const float* __restrict__ w,
                              const float* __restrict__ ns,
                              unsigned int* __restrict__ wbf)
{
    const int i = (blockIdx.x * 256 + threadIdx.x) * 4;
    const float4 wv = *reinterpret_cast<const float4*>(w + i);
    const float4 nv = *reinterpret_cast<const float4*>(ns + (i & 4095));
    uint2 o;
    o.x = pack_bf16x2(wv.x * nv.x, wv.y * nv.y);
    o.y = pack_bf16x2(wv.z * nv.z, wv.w * nv.w);
    *reinterpret_cast<uint2*>(wbf + (i >> 1)) = o;
}

// ================= Kernel A: compute per-token 4x4 combine matrix M =========
// 16 tokens/block (all 16 MFMA A-rows used, no duplication), 8-way split-K,
// depth-2 software-pipelined loads. Reads streams exactly once.
__global__ __launch_bounds__(512)
void compute_M(const float* __restrict__ streams,
               const unsigned short* __restrict__ wbf,   // scaled bf16 W [48][4096]
               const float* __restrict__ proj_b,
               const float* __restrict__ out_scale,
               float* __restrict__ Mout)
{
    __shared__ float red[8][3][16][16];   // [kpart][ntile][tokenrow][col] = 24 KB
    __shared__ float ssq_red[8][16];      // [kpart][token]

    const int tid  = threadIdx.x;
    const int wv   = tid >> 6;            // wave == K-part
    const int lane = tid & 63;
    const size_t tok0 = (size_t)blockIdx.x * 16;

    // ---------- MFMA projection ----------
    {
        const int r = lane & 15;          // token row == B column
        const int g = lane >> 4;          // k-subgroup
        const int koff = g * 8;
        const int kbase = wv * 512;       // this wave's K eighth

        const float* ap = streams + (tok0 + r) * 4096 + kbase + koff;
        const unsigned short* wp = wbf + (size_t)r * 4096 + kbase + koff;

        f32x4 acc0 = {0.f, 0.f, 0.f, 0.f};
        f32x4 acc1 = acc0, acc2 = acc0;
        float ssq = 0.f;

        // depth-2 pipeline: prefetch ks+1 while computing ks
        float4 pa0 = *reinterpret_cast<const float4*>(ap);
        float4 pa1 = *reinterpret_cast<const float4*>(ap + 4);
        bf16x8 pb0 = *reinterpret_cast<const bf16x8*>(wp);
        bf16x8 pb1 = *reinterpret_cast<const bf16x8*>(wp + 16 * 4096);
        bf16x8 pb2 = *reinterpret_cast<const bf16x8*>(wp + 32 * 4096);

        #pragma unroll
        for (int ks = 0; ks < 16; ++ks) {
            const float4 a0 = pa0, a1 = pa1;
            const bf16x8 b0 = pb0, b1 = pb1, b2 = pb2;
            if (ks < 15) {
                pa0 = *reinterpret_cast<const float4*>(ap + (ks + 1) * 32);
                pa1 = *reinterpret_cast<const float4*>(ap + (ks + 1) * 32 + 4);
                pb0 = *reinterpret_cast<const bf16x8*>(wp + (ks + 1) * 32);
                pb1 = *reinterpret_cast<const bf16x8*>(wp + 16 * 4096 + (ks + 1) * 32);
                pb2 = *reinterpret_cast<const bf16x8*>(wp + 32 * 4096 + (ks + 1) * 32);
            }
            ssq = fmaf(a0.x, a0.x, ssq); ssq = fmaf(a0.y, a0.y, ssq);
            ssq = fmaf(a0.z, a0.z, ssq); ssq = fmaf(a0.w, a0.w, ssq);
            ssq = fmaf(a1.x, a1.x, ssq); ssq = fmaf(a1.y, a1.y, ssq);
            ssq = fmaf(a1.z, a1.z, ssq); ssq = fmaf(a1.w, a1.w, ssq);
            bf16x8 a;
            a[0] = (__bf16)a0.x; a[1] = (__bf16)a0.y; a[2] = (__bf16)a0.z; a[3] = (__bf16)a0.w;
            a[4] = (__bf16)a1.x; a[5] = (__bf16)a1.y; a[6] = (__bf16)a1.z; a[7] = (__bf16)a1.w;
            acc0 = __builtin_amdgcn_mfma_f32_16x16x32_bf16(a, b0, acc0, 0, 0, 0);
            acc1 = __builtin_amdgcn_mfma_f32_16x16x32_bf16(a, b1, acc1, 0, 0, 0);
            acc2 = __builtin_amdgcn_mfma_f32_16x16x32_bf16(a, b2, acc2, 0, 0, 0);
        }

        // ssq: lanes {l, l^16, l^32, l^48} are the 4 k-subgroups of token r.
        ssq += __shfl_xor(ssq, 16, 64);
        ssq += __shfl_xor(ssq, 32, 64);
        if (lane < 16) ssq_red[wv][lane] = ssq;

        // D layout: col=lane&15, row=(lane>>4)*4+reg; row == token 0..15
        #pragma unroll
        for (int rr = 0; rr < 4; ++rr) {
            red[wv][0][g * 4 + rr][r] = acc0[rr];
            red[wv][1][g * 4 + rr][r] = acc1[rr];
            red[wv][2][g * 4 + rr][r] = acc2[rr];
        }
    }
    __syncthreads();   // the only barrier

    // ---------- each half-wave builds M for one token (reg-only) ----------
    const int t = wv * 2 + (lane >> 5);   // wave wv handles tokens 2wv, 2wv+1
    float Mr[16];
    {
        float st = 0.f;
        #pragma unroll
        for (int kp = 0; kp < 8; ++kp) st += ssq_red[kp][t];
        const float invr = rsqrtf(st * (1.f / 4096.f) + EPS_F);

        #define REDUCE_TILE(tile, raw)                                             \
            {                                                                      \
                _Pragma("unroll")                                                  \
                for (int c4 = 0; c4 < 4; ++c4) {                                   \
                    f32x4 s = {0.f, 0.f, 0.f, 0.f};                                \
                    _Pragma("unroll")                                              \
                    for (int kp = 0; kp < 8; ++kp)                                 \
                        s += *reinterpret_cast<const f32x4*>(&red[kp][tile][t][c4 * 4]); \
                    const float4 pb = *reinterpret_cast<const float4*>(&proj_b[tile * 16 + c4 * 4]); \
                    raw[c4*4 + 0] = s[0] * invr + pb.x;                            \
                    raw[c4*4 + 1] = s[1] * invr + pb.y;                            \
                    raw[c4*4 + 2] = s[2] * invr + pb.z;                            \
                    raw[c4*4 + 3] = s[3] * invr + pb.w;                            \
                }                                                                  \
            }

        // H_pre row-softmax -> c[j] = 0.25 * column sums
        float c[4] = {0.f, 0.f, 0.f, 0.f};
        {
            float raw[16];
            REDUCE_TILE(0, raw)
            #pragma unroll
            for (int i = 0; i < 4; ++i) {
                const float a0 = raw[i*4+0], a1 = raw[i*4+1], a2 = raw[i*4+2], a3 = raw[i*4+3];
                const float m = fmaxf(fmaxf(a0, a1), fmaxf(a2, a3));
                const float e0 = expf(a0 - m), e1 = expf(a1 - m);
                const float e2 = expf(a2 - m), e3 = expf(a3 - m);
                const float inv = 1.f / (e0 + e1 + e2 + e3);
                c[0] = fmaf(e0, inv, c[0]); c[1] = fmaf(e1, inv, c[1]);
                c[2] = fmaf(e2, inv, c[2]); c[3] = fmaf(e3, inv, c[3]);
            }
            c[0] *= 0.25f; c[1] *= 0.25f; c[2] *= 0.25f; c[3] *= 0.25f;
        }

        // H_post column-softmax -> rs[i] = row sums
        float rs[4] = {0.f, 0.f, 0.f, 0.f};
        {
            float raw[16];
            REDUCE_TILE(1, raw)
            #pragma unroll
            for (int j = 0; j < 4; ++j) {
                const float b0 = raw[j], b1 = raw[4+j], b2 = raw[8+j], b3 = raw[12+j];
                const float m = fmaxf(fmaxf(b0, b1), fmaxf(b2, b3));
                const float e0 = expf(b0 - m), e1 = expf(b1 - m);
                const float e2 = expf(b2 - m), e3 = expf(b3 - m);
                const float inv = 1.f / (e0 + e1 + e2 + e3);
                rs[0] = fmaf(e0, inv, rs[0]); rs[1] = fmaf(e1, inv, rs[1]);
                rs[2] = fmaf(e2, inv, rs[2]); rs[3] = fmaf(e3, inv, rs[3]);
            }
        }

        // Cayley iterative
        float W[16], Y[16];
        {
            float raw[16];
            REDUCE_TILE(2, raw)
            #pragma unroll
            for (int i = 0; i < 4; ++i)
                #pragma unroll
                for (int j = 0; j < 4; ++j)
                    W[i*4+j] = raw[i*4+j] - raw[j*4+i];
        }
        #pragma unroll
        for (int i = 0; i < 16; ++i) Y[i] = 0.1f * W[i];
        Y[0] += 1.f; Y[5] += 1.f; Y[10] += 1.f; Y[15] += 1.f;
        #pragma unroll
        for (int it = 0; it < 2; ++it) {
            float T1[16];
            #pragma unroll
            for (int i = 0; i < 16; ++i) T1[i] = Y[i];
            T1[0] += 1.f; T1[5] += 1.f; T1[10] += 1.f; T1[15] += 1.f;
            float Yn[16];
            #pragma unroll
            for (int i = 0; i < 4; ++i)
                #pragma unroll
                for (int j = 0; j < 4; ++j) {
                    float s = W[i*4+0] * T1[0*4+j];
                    s = fmaf(W[i*4+1], T1[1*4+j], s);
                    s = fmaf(W[i*4+2], T1[2*4+j], s);
                    s = fmaf(W[i*4+3], T1[3*4+j], s);
                    Yn[i*4+j] = ((i == j) ? 1.f : 0.f) + 0.05f * s;
                }
            #pragma unroll
            for (int i = 0; i < 16; ++i) Y[i] = Yn[i];
        }

        const float os = out_scale[0];
        #pragma unroll
        for (int i = 0; i < 4; ++i)
            #pragma unroll
            for (int j = 0; j < 4; ++j)
                Mr[i*4+j] = Y[i*4+j] + os * rs[i] * c[j];
        #undef REDUCE_TILE
    }

    if ((lane & 31) == 0) {   // lane 0 -> token 2wv, lane 32 -> token 2wv+1
        float* mp = Mout + (tok0 + t) * 16;
        *reinterpret_cast<float4*>(mp +  0) = make_float4(Mr[0],  Mr[1],  Mr[2],  Mr[3]);
        *reinterpret_cast<float4*>(mp +  4) = make_float4(Mr[4],  Mr[5],  Mr[6],  Mr[7]);
        *reinterpret_cast<float4*>(mp +  8) = make_float4(Mr[8],  Mr[9],  Mr[10], Mr[11]);
        *reinterpret_cast<float4*>(mp + 12) = make_float4(Mr[12], Mr[13], Mr[14], Mr[15]);
    }
}

// ================= Kernel B: out[t] = M[t] @ streams[t] — pure streaming ====
static __device__ __forceinline__ float4 mix4(float4 m, float4 x0, float4 x1,
                                              float4 x2, float4 x3) {
    float4 o;
    o.x = fmaf(m.w, x3.x, fmaf(m.z, x2.x, fmaf(m.y, x1.x, m.x * x0.x)));
    o.y = fmaf(m.w, x3.y, fmaf(m.z, x2.y, fmaf(m.y, x1.y, m.x * x0.y)));
    o.z = fmaf(m.w, x3.z, fmaf(m.z, x2.z, fmaf(m.y, x1.z, m.x * x0.z)));
    o.w = fmaf(m.w, x3.w, fmaf(m.z, x2.w, fmaf(m.y, x1.w, m.x * x0.w)));
    return o;
}

__global__ __launch_bounds__(256)
void apply_M(const float* __restrict__ streams,
             const float* __restrict__ Mfull,
             float* __restrict__ out)
{
    const size_t t = blockIdx.x;           // token
    const int c = threadIdx.x * 4;         // column quad

    const float4* mp = reinterpret_cast<const float4*>(Mfull + t * 16);
    const float4 m0 = mp[0], m1 = mp[1], m2 = mp[2], m3 = mp[3];

    const float* src = streams + t * 4096;
    float* dst = out + t * 4096;

    const float4 x0 = *reinterpret_cast<const float4*>(src + c);
    const float4 x1 = *reinterpret_cast<const float4*>(src + 1024 + c);
    const float4 x2 = *reinterpret_cast<const float4*>(src + 2048 + c);
    const float4 x3 = *reinterpret_cast<const float4*>(src + 3072 + c);

    *reinterpret_cast<float4*>(dst +        c) = mix4(m0, x0, x1, x2, x3);
    *reinterpret_cast<float4*>(dst + 1024 + c) = mix4(m1, x0, x1, x2, x3);
    *reinterpret_cast<float4*>(dst + 2048 + c) = mix4(m2, x0, x1, x2, x3);
    *reinterpret_cast<float4*>(dst + 3072 + c) = mix4(m3, x0, x1, x2, x3);
}

extern "C" void kernel_launch(void* const* d_in, const int* in_sizes, int n_in,
                              void* d_out, int out_size, void* d_ws, size_t ws_size,
                              hipStream_t stream) {
    const float* streams    = (const float*)d_in[0];
    const float* norm_scale = (const float*)d_in[1];
    const float* proj_w     = (const float*)d_in[2];
    const float* proj_b     = (const float*)d_in[3];
    const float* out_scale  = (const float*)d_in[4];
    float* outp = (float*)d_out;

    unsigned int* wbf = (unsigned int*)d_ws;                    // 393216 B
    float* Mfull = (float*)((char*)d_ws + 393216);              // 16384*16*4 = 1 MB

    scale_weights<<<dim3(192), 256, 0, stream>>>(proj_w, norm_scale, wbf);

    const int n_tok = in_sizes[0] / 4096;          // B*S = 16384
    compute_M<<<dim3(n_tok / 16), 512, 0, stream>>>(streams,
                                                    (const unsigned short*)wbf,
                                                    proj_b, out_scale, Mfull);
    apply_M<<<dim3(n_tok), 256, 0, stream>>>(streams, Mfull, outp);
}

// Round 11
// 175.419 us; speedup vs baseline: 1.4959x; 1.0884x over previous
//
#include <hip/hip_runtime.h>
#include <hip/hip_bf16.h>

#define EPS_F 1e-5f

typedef __bf16 bf16x8 __attribute__((ext_vector_type(8)));
typedef float f32x4 __attribute__((ext_vector_type(4)));

static __device__ __forceinline__ unsigned int pack_bf16x2(float a, float b) {
    union { float f; unsigned int u; } ca, cb;
    ca.f = a; cb.f = b;
    unsigned int ua = (ca.u + 0x7fffu + ((ca.u >> 16) & 1u)) >> 16;
    unsigned int ub = (cb.u + 0x7fffu + ((cb.u >> 16) & 1u)) >> 16;
    return ua | (ub << 16);
}

// ---- setup: wbf[n][k] = bf16(proj_w[n][k] * norm_scale[k]), [48][4096] ----
__global__ void scale_weights(const float* __restrict__ w,
                              const float* __restrict__ ns,
                              unsigned int* __restrict__ wbf)
{
    const int i = (blockIdx.x * 256 + threadIdx.x) * 4;
    const float4 wv = *reinterpret_cast<const float4*>(w + i);
    const float4 nv = *reinterpret_cast<const float4*>(ns + (i & 4095));
    uint2 o;
    o.x = pack_bf16x2(wv.x * nv.x, wv.y * nv.y);
    o.y = pack_bf16x2(wv.z * nv.z, wv.w * nv.w);
    *reinterpret_cast<uint2*>(wbf + (i >> 1)) = o;
}

// ================= Kernel A: compute per-token 4x4 combine matrix M =========
// 16 tokens/block, 8-way split-K. Streams read once. K-loop = 2 passes of 8
// ks-steps; each pass issues ALL 16 A-loads up-front (sched_barrier-pinned)
// so ~8 line-pairs/wave stay in flight instead of depth-2.
__global__ __launch_bounds__(512)
void compute_M(const float* __restrict__ streams,
               const unsigned short* __restrict__ wbf,   // scaled bf16 W [48][4096]
               const float* __restrict__ proj_b,
               const float* __restrict__ out_scale,
               float* __restrict__ Mout)
{
    __shared__ float red[8][3][16][16];   // [kpart][ntile][tokenrow][col] = 24 KB
    __shared__ float ssq_red[8][16];      // [kpart][token]

    const int tid  = threadIdx.x;
    const int wv   = tid >> 6;            // wave == K-part
    const int lane = tid & 63;
    const size_t tok0 = (size_t)blockIdx.x * 16;

    // ---------- MFMA projection ----------
    {
        const int r = lane & 15;          // token row == B column
        const int g = lane >> 4;          // k-subgroup
        const int koff = g * 8;
        const int kbase = wv * 512;       // this wave's K eighth

        const float* ap = streams + (tok0 + r) * 4096 + kbase + koff;
        const unsigned short* wp = wbf + (size_t)r * 4096 + kbase + koff;

        f32x4 acc0 = {0.f, 0.f, 0.f, 0.f};
        f32x4 acc1 = acc0, acc2 = acc0;
        float ssq = 0.f;

        // rolling depth-2 prefetch for B (L2-resident weights)
        bf16x8 pb0 = *reinterpret_cast<const bf16x8*>(wp);
        bf16x8 pb1 = *reinterpret_cast<const bf16x8*>(wp + 16 * 4096);
        bf16x8 pb2 = *reinterpret_cast<const bf16x8*>(wp + 32 * 4096);

        #pragma unroll 1
        for (int p = 0; p < 2; ++p) {
            // issue all 16 stream loads of this pass back-to-back
            f32x4 ar[16];
            #pragma unroll
            for (int q = 0; q < 8; ++q) {
                ar[2 * q]     = *reinterpret_cast<const f32x4*>(ap + (p * 8 + q) * 32);
                ar[2 * q + 1] = *reinterpret_cast<const f32x4*>(ap + (p * 8 + q) * 32 + 4);
            }
            __builtin_amdgcn_sched_barrier(0);   // pin: loads stay issued up-front

            #pragma unroll
            for (int q = 0; q < 8; ++q) {
                const int ks = p * 8 + q;
                const bf16x8 b0 = pb0, b1 = pb1, b2 = pb2;
                if (ks < 15) {
                    pb0 = *reinterpret_cast<const bf16x8*>(wp + (ks + 1) * 32);
                    pb1 = *reinterpret_cast<const bf16x8*>(wp + 16 * 4096 + (ks + 1) * 32);
                    pb2 = *reinterpret_cast<const bf16x8*>(wp + 32 * 4096 + (ks + 1) * 32);
                }
                const f32x4 a0 = ar[2 * q], a1 = ar[2 * q + 1];
                ssq = fmaf(a0[0], a0[0], ssq); ssq = fmaf(a0[1], a0[1], ssq);
                ssq = fmaf(a0[2], a0[2], ssq); ssq = fmaf(a0[3], a0[3], ssq);
                ssq = fmaf(a1[0], a1[0], ssq); ssq = fmaf(a1[1], a1[1], ssq);
                ssq = fmaf(a1[2], a1[2], ssq); ssq = fmaf(a1[3], a1[3], ssq);
                bf16x8 a;
                a[0] = (__bf16)a0[0]; a[1] = (__bf16)a0[1]; a[2] = (__bf16)a0[2]; a[3] = (__bf16)a0[3];
                a[4] = (__bf16)a1[0]; a[5] = (__bf16)a1[1]; a[6] = (__bf16)a1[2]; a[7] = (__bf16)a1[3];
                acc0 = __builtin_amdgcn_mfma_f32_16x16x32_bf16(a, b0, acc0, 0, 0, 0);
                acc1 = __builtin_amdgcn_mfma_f32_16x16x32_bf16(a, b1, acc1, 0, 0, 0);
                acc2 = __builtin_amdgcn_mfma_f32_16x16x32_bf16(a, b2, acc2, 0, 0, 0);
            }
        }

        // ssq: lanes {l, l^16, l^32, l^48} are the 4 k-subgroups of token r.
        ssq += __shfl_xor(ssq, 16, 64);
        ssq += __shfl_xor(ssq, 32, 64);
        if (lane < 16) ssq_red[wv][lane] = ssq;

        // D layout: col=lane&15, row=(lane>>4)*4+reg; row == token 0..15
        #pragma unroll
        for (int rr = 0; rr < 4; ++rr) {
            red[wv][0][g * 4 + rr][r] = acc0[rr];
            red[wv][1][g * 4 + rr][r] = acc1[rr];
            red[wv][2][g * 4 + rr][r] = acc2[rr];
        }
    }
    __syncthreads();   // the only barrier

    // ---------- each half-wave builds M for one token (reg-only) ----------
    const int t = wv * 2 + (lane >> 5);   // wave wv handles tokens 2wv, 2wv+1
    float Mr[16];
    {
        float st = 0.f;
        #pragma unroll
        for (int kp = 0; kp < 8; ++kp) st += ssq_red[kp][t];
        const float invr = rsqrtf(st * (1.f / 4096.f) + EPS_F);

        #define REDUCE_TILE(tile, raw)                                             \
            {                                                                      \
                _Pragma("unroll")                                                  \
                for (int c4 = 0; c4 < 4; ++c4) {                                   \
                    f32x4 s = {0.f, 0.f, 0.f, 0.f};                                \
                    _Pragma("unroll")                                              \
                    for (int kp = 0; kp < 8; ++kp)                                 \
                        s += *reinterpret_cast<const f32x4*>(&red[kp][tile][t][c4 * 4]); \
                    const float4 pb = *reinterpret_cast<const float4*>(&proj_b[tile * 16 + c4 * 4]); \
                    raw[c4*4 + 0] = s[0] * invr + pb.x;                            \
                    raw[c4*4 + 1] = s[1] * invr + pb.y;                            \
                    raw[c4*4 + 2] = s[2] * invr + pb.z;                            \
                    raw[c4*4 + 3] = s[3] * invr + pb.w;                            \
                }                                                                  \
            }

        // H_pre row-softmax -> c[j] = 0.25 * column sums
        float c[4] = {0.f, 0.f, 0.f, 0.f};
        {
            float raw[16];
            REDUCE_TILE(0, raw)
            #pragma unroll
            for (int i = 0; i < 4; ++i) {
                const float a0 = raw[i*4+0], a1 = raw[i*4+1], a2 = raw[i*4+2], a3 = raw[i*4+3];
                const float m = fmaxf(fmaxf(a0, a1), fmaxf(a2, a3));
                const float e0 = expf(a0 - m), e1 = expf(a1 - m);
                const float e2 = expf(a2 - m), e3 = expf(a3 - m);
                const float inv = 1.f / (e0 + e1 + e2 + e3);
                c[0] = fmaf(e0, inv, c[0]); c[1] = fmaf(e1, inv, c[1]);
                c[2] = fmaf(e2, inv, c[2]); c[3] = fmaf(e3, inv, c[3]);
            }
            c[0] *= 0.25f; c[1] *= 0.25f; c[2] *= 0.25f; c[3] *= 0.25f;
        }

        // H_post column-softmax -> rs[i] = row sums
        float rs[4] = {0.f, 0.f, 0.f, 0.f};
        {
            float raw[16];
            REDUCE_TILE(1, raw)
            #pragma unroll
            for (int j = 0; j < 4; ++j) {
                const float b0 = raw[j], b1 = raw[4+j], b2 = raw[8+j], b3 = raw[12+j];
                const float m = fmaxf(fmaxf(b0, b1), fmaxf(b2, b3));
                const float e0 = expf(b0 - m), e1 = expf(b1 - m);
                const float e2 = expf(b2 - m), e3 = expf(b3 - m);
                const float inv = 1.f / (e0 + e1 + e2 + e3);
                rs[0] = fmaf(e0, inv, rs[0]); rs[1] = fmaf(e1, inv, rs[1]);
                rs[2] = fmaf(e2, inv, rs[2]); rs[3] = fmaf(e3, inv, rs[3]);
            }
        }

        // Cayley iterative
        float W[16], Y[16];
        {
            float raw[16];
            REDUCE_TILE(2, raw)
            #pragma unroll
            for (int i = 0; i < 4; ++i)
                #pragma unroll
                for (int j = 0; j < 4; ++j)
                    W[i*4+j] = raw[i*4+j] - raw[j*4+i];
        }
        #pragma unroll
        for (int i = 0; i < 16; ++i) Y[i] = 0.1f * W[i];
        Y[0] += 1.f; Y[5] += 1.f; Y[10] += 1.f; Y[15] += 1.f;
        #pragma unroll
        for (int it = 0; it < 2; ++it) {
            float T1[16];
            #pragma unroll
            for (int i = 0; i < 16; ++i) T1[i] = Y[i];
            T1[0] += 1.f; T1[5] += 1.f; T1[10] += 1.f; T1[15] += 1.f;
            float Yn[16];
            #pragma unroll
            for (int i = 0; i < 4; ++i)
                #pragma unroll
                for (int j = 0; j < 4; ++j) {
                    float s = W[i*4+0] * T1[0*4+j];
                    s = fmaf(W[i*4+1], T1[1*4+j], s);
                    s = fmaf(W[i*4+2], T1[2*4+j], s);
                    s = fmaf(W[i*4+3], T1[3*4+j], s);
                    Yn[i*4+j] = ((i == j) ? 1.f : 0.f) + 0.05f * s;
                }
            #pragma unroll
            for (int i = 0; i < 16; ++i) Y[i] = Yn[i];
        }

        const float os = out_scale[0];
        #pragma unroll
        for (int i = 0; i < 4; ++i)
            #pragma unroll
            for (int j = 0; j < 4; ++j)
                Mr[i*4+j] = Y[i*4+j] + os * rs[i] * c[j];
        #undef REDUCE_TILE
    }

    if ((lane & 31) == 0) {   // lane 0 -> token 2wv, lane 32 -> token 2wv+1
        float* mp = Mout + (tok0 + t) * 16;
        *reinterpret_cast<float4*>(mp +  0) = make_float4(Mr[0],  Mr[1],  Mr[2],  Mr[3]);
        *reinterpret_cast<float4*>(mp +  4) = make_float4(Mr[4],  Mr[5],  Mr[6],  Mr[7]);
        *reinterpret_cast<float4*>(mp +  8) = make_float4(Mr[8],  Mr[9],  Mr[10], Mr[11]);
        *reinterpret_cast<float4*>(mp + 12) = make_float4(Mr[12], Mr[13], Mr[14], Mr[15]);
    }
}

// ================= Kernel B: out[t] = M[t] @ streams[t] — pure streaming ====
static __device__ __forceinline__ f32x4 mix4(float4 m, f32x4 x0, f32x4 x1,
                                             f32x4 x2, f32x4 x3) {
    f32x4 o;
    #pragma unroll
    for (int e = 0; e < 4; ++e)
        o[e] = fmaf(m.w, x3[e], fmaf(m.z, x2[e], fmaf(m.y, x1[e], m.x * x0[e])));
    return o;
}

__global__ __launch_bounds__(256)
void apply_M(const float* __restrict__ streams,
             const float* __restrict__ Mfull,
             float* __restrict__ out)
{
    const size_t t = blockIdx.x;           // token
    const int c = threadIdx.x * 4;         // column quad

    const float4* mp = reinterpret_cast<const float4*>(Mfull + t * 16);
    const float4 m0 = mp[0], m1 = mp[1], m2 = mp[2], m3 = mp[3];

    const float* src = streams + t * 4096;
    float* dst = out + t * 4096;

    const f32x4 x0 = *reinterpret_cast<const f32x4*>(src + c);
    const f32x4 x1 = *reinterpret_cast<const f32x4*>(src + 1024 + c);
    const f32x4 x2 = *reinterpret_cast<const f32x4*>(src + 2048 + c);
    const f32x4 x3 = *reinterpret_cast<const f32x4*>(src + 3072 + c);

    // nontemporal: output is never re-read; don't evict the L3-warm streams
    __builtin_nontemporal_store(mix4(m0, x0, x1, x2, x3),
                                reinterpret_cast<f32x4*>(dst + c));
    __builtin_nontemporal_store(mix4(m1, x0, x1, x2, x3),
                                reinterpret_cast<f32x4*>(dst + 1024 + c));
    __builtin_nontemporal_store(mix4(m2, x0, x1, x2, x3),
                                reinterpret_cast<f32x4*>(dst + 2048 + c));
    __builtin_nontemporal_store(mix4(m3, x0, x1, x2, x3),
                                reinterpret_cast<f32x4*>(dst + 3072 + c));
}

extern "C" void kernel_launch(void* const* d_in, const int* in_sizes, int n_in,
                              void* d_out, int out_size, void* d_ws, size_t ws_size,
                              hipStream_t stream) {
    const float* streams    = (const float*)d_in[0];
    const float* norm_scale = (const float*)d_in[1];
    const float* proj_w     = (const float*)d_in[2];
    const float* proj_b     = (const float*)d_in[3];
    const float* out_scale  = (const float*)d_in[4];
    float* outp = (float*)d_out;

    unsigned int* wbf = (unsigned int*)d_ws;                    // 393216 B
    float* Mfull = (float*)((char*)d_ws + 393216);              // 16384*16*4 = 1 MB

    scale_weights<<<dim3(192), 256, 0, stream>>>(proj_w, norm_scale, wbf);

    const int n_tok = in_sizes[0] / 4096;          // B*S = 16384
    compute_M<<<dim3(n_tok / 16), 512, 0, stream>>>(streams,
                                                    (const unsigned short*)wbf,
                                                    proj_b, out_scale, Mfull);
    apply_M<<<dim3(n_tok), 256, 0, stream>>>(streams, Mfull, outp);
}

// Round 12
// 155.459 us; speedup vs baseline: 1.6879x; 1.1284x over previous
//
#include <hip/hip_runtime.h>
#include <hip/hip_bf16.h>

#define EPS_F 1e-5f

typedef __bf16 bf16x8 __attribute__((ext_vector_type(8)));
typedef float f32x4 __attribute__((ext_vector_type(4)));

static __device__ __forceinline__ unsigned int pack_bf16x2(float a, float b) {
    union { float f; unsigned int u; } ca, cb;
    ca.f = a; cb.f = b;
    unsigned int ua = (ca.u + 0x7fffu + ((ca.u >> 16) & 1u)) >> 16;
    unsigned int ub = (cb.u + 0x7fffu + ((cb.u >> 16) & 1u)) >> 16;
    return ua | (ub << 16);
}

// ---- setup: wbf[n][k] = bf16(proj_w[n][k] * norm_scale[k]), [48][4096] ----
__global__ void scale_weights(const float* __restrict__ w,
                              const float* __restrict__ ns,
                              unsigned int* __restrict__ wbf)
{
    const int i = (blockIdx.x * 256 + threadIdx.x) * 4;
    const float4 wv = *reinterpret_cast<const float4*>(w + i);
    const float4 nv = *reinterpret_cast<const float4*>(ns + (i & 4095));
    uint2 o;
    o.x = pack_bf16x2(wv.x * nv.x, wv.y * nv.y);
    o.y = pack_bf16x2(wv.z * nv.z, wv.w * nv.w);
    *reinterpret_cast<uint2*>(wbf + (i >> 1)) = o;
}

// ============ Fused: M-projection (MFMA) + 4x4 math + apply, one kernel =====
// 16 tokens/block, 512 threads. Phase 2 reads streams ONCE from HBM (pinned
// load batches). Phase 3 builds M per half-wave in registers. Phase 4 re-reads
// the same (cache-hot) stream lines and writes out — no second kernel, so
// early blocks' writes overlap late blocks' reads.
__global__ __launch_bounds__(512)
void fused_stream_mix(const float* __restrict__ streams,
                      const unsigned short* __restrict__ wbf,   // scaled bf16 W [48][4096]
                      const float* __restrict__ proj_b,
                      const float* __restrict__ out_scale,
                      float* __restrict__ out)
{
    __shared__ float red[8][3][16][16];   // [kpart][ntile][tokenrow][col] = 24 KB
    __shared__ float ssq_red[8][16];      // [kpart][token]

    const int tid  = threadIdx.x;
    const int wv   = tid >> 6;            // wave == K-part
    const int lane = tid & 63;
    const size_t tok0 = (size_t)blockIdx.x * 16;

    // ---------- Phase 2: MFMA projection, 8-way split-K, pinned load batches ----------
    {
        const int r = lane & 15;          // token row == B column
        const int g = lane >> 4;          // k-subgroup
        const int koff = g * 8;
        const int kbase = wv * 512;       // this wave's K eighth

        const float* ap = streams + (tok0 + r) * 4096 + kbase + koff;
        const unsigned short* wp = wbf + (size_t)r * 4096 + kbase + koff;

        f32x4 acc0 = {0.f, 0.f, 0.f, 0.f};
        f32x4 acc1 = acc0, acc2 = acc0;
        float ssq = 0.f;

        bf16x8 pb0 = *reinterpret_cast<const bf16x8*>(wp);
        bf16x8 pb1 = *reinterpret_cast<const bf16x8*>(wp + 16 * 4096);
        bf16x8 pb2 = *reinterpret_cast<const bf16x8*>(wp + 32 * 4096);

        #pragma unroll 1
        for (int p = 0; p < 2; ++p) {
            f32x4 ar[16];
            #pragma unroll
            for (int q = 0; q < 8; ++q) {
                ar[2 * q]     = *reinterpret_cast<const f32x4*>(ap + (p * 8 + q) * 32);
                ar[2 * q + 1] = *reinterpret_cast<const f32x4*>(ap + (p * 8 + q) * 32 + 4);
            }
            __builtin_amdgcn_sched_barrier(0);   // pin: loads stay issued up-front

            #pragma unroll
            for (int q = 0; q < 8; ++q) {
                const int ks = p * 8 + q;
                const bf16x8 b0 = pb0, b1 = pb1, b2 = pb2;
                if (ks < 15) {
                    pb0 = *reinterpret_cast<const bf16x8*>(wp + (ks + 1) * 32);
                    pb1 = *reinterpret_cast<const bf16x8*>(wp + 16 * 4096 + (ks + 1) * 32);
                    pb2 = *reinterpret_cast<const bf16x8*>(wp + 32 * 4096 + (ks + 1) * 32);
                }
                const f32x4 a0 = ar[2 * q], a1 = ar[2 * q + 1];
                ssq = fmaf(a0[0], a0[0], ssq); ssq = fmaf(a0[1], a0[1], ssq);
                ssq = fmaf(a0[2], a0[2], ssq); ssq = fmaf(a0[3], a0[3], ssq);
                ssq = fmaf(a1[0], a1[0], ssq); ssq = fmaf(a1[1], a1[1], ssq);
                ssq = fmaf(a1[2], a1[2], ssq); ssq = fmaf(a1[3], a1[3], ssq);
                bf16x8 a;
                a[0] = (__bf16)a0[0]; a[1] = (__bf16)a0[1]; a[2] = (__bf16)a0[2]; a[3] = (__bf16)a0[3];
                a[4] = (__bf16)a1[0]; a[5] = (__bf16)a1[1]; a[6] = (__bf16)a1[2]; a[7] = (__bf16)a1[3];
                acc0 = __builtin_amdgcn_mfma_f32_16x16x32_bf16(a, b0, acc0, 0, 0, 0);
                acc1 = __builtin_amdgcn_mfma_f32_16x16x32_bf16(a, b1, acc1, 0, 0, 0);
                acc2 = __builtin_amdgcn_mfma_f32_16x16x32_bf16(a, b2, acc2, 0, 0, 0);
            }
        }

        ssq += __shfl_xor(ssq, 16, 64);
        ssq += __shfl_xor(ssq, 32, 64);
        if (lane < 16) ssq_red[wv][lane] = ssq;

        // D layout: col=lane&15, row=(lane>>4)*4+reg; row == token 0..15
        #pragma unroll
        for (int rr = 0; rr < 4; ++rr) {
            red[wv][0][g * 4 + rr][r] = acc0[rr];
            red[wv][1][g * 4 + rr][r] = acc1[rr];
            red[wv][2][g * 4 + rr][r] = acc2[rr];
        }
    }
    __syncthreads();   // the only barrier

    // ---------- Phase 3+4 setup: half-wave owns token t ----------
    const int t  = wv * 2 + (lane >> 5);  // wave wv -> tokens 2wv, 2wv+1
    const int l5 = lane & 31;
    const float* src = streams + (tok0 + t) * 4096;
    float* dst = out + (tok0 + t) * 4096;

    // issue first phase-4 load batch NOW; phase-3 math (~250 VALU) hides it
    f32x4 px0 = *reinterpret_cast<const f32x4*>(src + l5 * 4);
    f32x4 px1 = *reinterpret_cast<const f32x4*>(src + 1024 + l5 * 4);
    f32x4 px2 = *reinterpret_cast<const f32x4*>(src + 2048 + l5 * 4);
    f32x4 px3 = *reinterpret_cast<const f32x4*>(src + 3072 + l5 * 4);

    // ---------- Phase 3: build M in registers (redundant per half-wave) ----------
    float Mr[16];
    {
        float st = 0.f;
        #pragma unroll
        for (int kp = 0; kp < 8; ++kp) st += ssq_red[kp][t];
        const float invr = rsqrtf(st * (1.f / 4096.f) + EPS_F);

        #define REDUCE_TILE(tile, raw)                                             \
            {                                                                      \
                _Pragma("unroll")                                                  \
                for (int c4 = 0; c4 < 4; ++c4) {                                   \
                    f32x4 s = {0.f, 0.f, 0.f, 0.f};                                \
                    _Pragma("unroll")                                              \
                    for (int kp = 0; kp < 8; ++kp)                                 \
                        s += *reinterpret_cast<const f32x4*>(&red[kp][tile][t][c4 * 4]); \
                    const float4 pb = *reinterpret_cast<const float4*>(&proj_b[tile * 16 + c4 * 4]); \
                    raw[c4*4 + 0] = s[0] * invr + pb.x;                            \
                    raw[c4*4 + 1] = s[1] * invr + pb.y;                            \
                    raw[c4*4 + 2] = s[2] * invr + pb.z;                            \
                    raw[c4*4 + 3] = s[3] * invr + pb.w;                            \
                }                                                                  \
            }

        float c[4] = {0.f, 0.f, 0.f, 0.f};
        {
            float raw[16];
            REDUCE_TILE(0, raw)
            #pragma unroll
            for (int i = 0; i < 4; ++i) {
                const float a0 = raw[i*4+0], a1 = raw[i*4+1], a2 = raw[i*4+2], a3 = raw[i*4+3];
                const float m = fmaxf(fmaxf(a0, a1), fmaxf(a2, a3));
                const float e0 = expf(a0 - m), e1 = expf(a1 - m);
                const float e2 = expf(a2 - m), e3 = expf(a3 - m);
                const float inv = 1.f / (e0 + e1 + e2 + e3);
                c[0] = fmaf(e0, inv, c[0]); c[1] = fmaf(e1, inv, c[1]);
                c[2] = fmaf(e2, inv, c[2]); c[3] = fmaf(e3, inv, c[3]);
            }
            c[0] *= 0.25f; c[1] *= 0.25f; c[2] *= 0.25f; c[3] *= 0.25f;
        }

        float rs[4] = {0.f, 0.f, 0.f, 0.f};
        {
            float raw[16];
            REDUCE_TILE(1, raw)
            #pragma unroll
            for (int j = 0; j < 4; ++j) {
                const float b0 = raw[j], b1 = raw[4+j], b2 = raw[8+j], b3 = raw[12+j];
                const float m = fmaxf(fmaxf(b0, b1), fmaxf(b2, b3));
                const float e0 = expf(b0 - m), e1 = expf(b1 - m);
                const float e2 = expf(b2 - m), e3 = expf(b3 - m);
                const float inv = 1.f / (e0 + e1 + e2 + e3);
                rs[0] = fmaf(e0, inv, rs[0]); rs[1] = fmaf(e1, inv, rs[1]);
                rs[2] = fmaf(e2, inv, rs[2]); rs[3] = fmaf(e3, inv, rs[3]);
            }
        }

        float W[16], Y[16];
        {
            float raw[16];
            REDUCE_TILE(2, raw)
            #pragma unroll
            for (int i = 0; i < 4; ++i)
                #pragma unroll
                for (int j = 0; j < 4; ++j)
                    W[i*4+j] = raw[i*4+j] - raw[j*4+i];
        }
        #pragma unroll
        for (int i = 0; i < 16; ++i) Y[i] = 0.1f * W[i];
        Y[0] += 1.f; Y[5] += 1.f; Y[10] += 1.f; Y[15] += 1.f;
        #pragma unroll
        for (int it = 0; it < 2; ++it) {
            float T1[16];
            #pragma unroll
            for (int i = 0; i < 16; ++i) T1[i] = Y[i];
            T1[0] += 1.f; T1[5] += 1.f; T1[10] += 1.f; T1[15] += 1.f;
            float Yn[16];
            #pragma unroll
            for (int i = 0; i < 4; ++i)
                #pragma unroll
                for (int j = 0; j < 4; ++j) {
                    float s = W[i*4+0] * T1[0*4+j];
                    s = fmaf(W[i*4+1], T1[1*4+j], s);
                    s = fmaf(W[i*4+2], T1[2*4+j], s);
                    s = fmaf(W[i*4+3], T1[3*4+j], s);
                    Yn[i*4+j] = ((i == j) ? 1.f : 0.f) + 0.05f * s;
                }
            #pragma unroll
            for (int i = 0; i < 16; ++i) Y[i] = Yn[i];
        }

        const float os = out_scale[0];
        #pragma unroll
        for (int i = 0; i < 4; ++i)
            #pragma unroll
            for (int j = 0; j < 4; ++j)
                Mr[i*4+j] = Y[i*4+j] + os * rs[i] * c[j];
        #undef REDUCE_TILE
    }

    // ---------- Phase 4: out[t] = M @ streams[t], cache-hot re-read ----------
    #pragma unroll 2
    for (int cq = 0; cq < 8; ++cq) {
        const f32x4 x0 = px0, x1 = px1, x2 = px2, x3 = px3;
        if (cq < 7) {
            const int ncol = (cq + 1) * 128 + l5 * 4;
            px0 = *reinterpret_cast<const f32x4*>(src + ncol);
            px1 = *reinterpret_cast<const f32x4*>(src + 1024 + ncol);
            px2 = *reinterpret_cast<const f32x4*>(src + 2048 + ncol);
            px3 = *reinterpret_cast<const f32x4*>(src + 3072 + ncol);
        }
        const int col = cq * 128 + l5 * 4;
        #pragma unroll
        for (int i = 0; i < 4; ++i) {
            f32x4 o;
            #pragma unroll
            for (int e = 0; e < 4; ++e)
                o[e] = fmaf(Mr[i*4+3], x3[e],
                        fmaf(Mr[i*4+2], x2[e],
                          fmaf(Mr[i*4+1], x1[e], Mr[i*4+0] * x0[e])));
            __builtin_nontemporal_store(o, reinterpret_cast<f32x4*>(dst + i * 1024 + col));
        }
    }
}

extern "C" void kernel_launch(void* const* d_in, const int* in_sizes, int n_in,
                              void* d_out, int out_size, void* d_ws, size_t ws_size,
                              hipStream_t stream) {
    const float* streams    = (const float*)d_in[0];
    const float* norm_scale = (const float*)d_in[1];
    const float* proj_w     = (const float*)d_in[2];
    const float* proj_b     = (const float*)d_in[3];
    const float* out_scale  = (const float*)d_in[4];
    float* outp = (float*)d_out;

    unsigned int* wbf = (unsigned int*)d_ws;       // 48*4096 bf16 = 393216 B

    scale_weights<<<dim3(192), 256, 0, stream>>>(proj_w, norm_scale, wbf);

    const int n_tok = in_sizes[0] / 4096;          // B*S = 16384
    fused_stream_mix<<<dim3(n_tok / 16), 512, 0, stream>>>(streams,
                                                           (const unsigned short*)wbf,
                                                           proj_b, out_scale, outp);
}

// Round 13
// 145.429 us; speedup vs baseline: 1.8044x; 1.0690x over previous
//
#include <hip/hip_runtime.h>
#include <hip/hip_bf16.h>

#define EPS_F 1e-5f

typedef __bf16 bf16x8 __attribute__((ext_vector_type(8)));
typedef float f32x4 __attribute__((ext_vector_type(4)));

static __device__ __forceinline__ unsigned int pack_bf16x2(float a, float b) {
    union { float f; unsigned int u; } ca, cb;
    ca.f = a; cb.f = b;
    unsigned int ua = (ca.u + 0x7fffu + ((ca.u >> 16) & 1u)) >> 16;
    unsigned int ub = (cb.u + 0x7fffu + ((cb.u >> 16) & 1u)) >> 16;
    return ua | (ub << 16);
}

// ---- setup: wbf[n][k] = bf16(proj_w[n][k] * norm_scale[k]), [48][4096] ----
__global__ void scale_weights(const float* __restrict__ w,
                              const float* __restrict__ ns,
                              unsigned int* __restrict__ wbf)
{
    const int i = (blockIdx.x * 256 + threadIdx.x) * 4;
    const float4 wv = *reinterpret_cast<const float4*>(w + i);
    const float4 nv = *reinterpret_cast<const float4*>(ns + (i & 4095));
    uint2 o;
    o.x = pack_bf16x2(wv.x * nv.x, wv.y * nv.y);
    o.y = pack_bf16x2(wv.z * nv.z, wv.w * nv.w);
    *reinterpret_cast<uint2*>(wbf + (i >> 1)) = o;
}

// ============ Fused: M-projection (MFMA) + 4x4 math + apply, one kernel =====
__global__ __launch_bounds__(512)
void fused_stream_mix(const float* __restrict__ streams,
                      const unsigned short* __restrict__ wbf,   // scaled bf16 W [48][4096]
                      const float* __restrict__ proj_b,
                      const float* __restrict__ out_scale,
                      float* __restrict__ out)
{
    __shared__ float red[8][3][16][16];   // [kpart][ntile][tokenrow][col] = 24 KB
    __shared__ float ssq_red[8][16];      // [kpart][token]

    const int tid  = threadIdx.x;
    const int wv   = tid >> 6;            // wave == K-part
    const int lane = tid & 63;
    const size_t tok0 = (size_t)blockIdx.x * 16;

    // ---------- Phase 2: MFMA projection, 8-way split-K, 4x4 pinned batches ----------
    {
        const int r = lane & 15;          // token row == B column
        const int g = lane >> 4;          // k-subgroup
        const int koff = g * 8;
        const int kbase = wv * 512;       // this wave's K eighth

        const float* ap = streams + (tok0 + r) * 4096 + kbase + koff;
        const unsigned short* wp = wbf + (size_t)r * 4096 + kbase + koff;

        f32x4 acc0 = {0.f, 0.f, 0.f, 0.f};
        f32x4 acc1 = acc0, acc2 = acc0;
        float ssq = 0.f;

        #pragma unroll 1
        for (int p = 0; p < 4; ++p) {
            // batch-issue this pass's 8 A-loads (HBM) + 12 B-loads (L2)
            f32x4 ar[8];
            bf16x8 br[12];
            #pragma unroll
            for (int q = 0; q < 4; ++q) {
                const int ks = p * 4 + q;
                ar[2 * q]     = *reinterpret_cast<const f32x4*>(ap + ks * 32);
                ar[2 * q + 1] = *reinterpret_cast<const f32x4*>(ap + ks * 32 + 4);
                br[3 * q]     = *reinterpret_cast<const bf16x8*>(wp + ks * 32);
                br[3 * q + 1] = *reinterpret_cast<const bf16x8*>(wp + 16 * 4096 + ks * 32);
                br[3 * q + 2] = *reinterpret_cast<const bf16x8*>(wp + 32 * 4096 + ks * 32);
            }
            // keep-alive: asm USES every loaded value -> no IR pass can sink the
            // loads below this point (sched_barrier alone was defeated, R12).
            asm volatile("" ::
                "v"(ar[0]), "v"(ar[1]), "v"(ar[2]), "v"(ar[3]),
                "v"(ar[4]), "v"(ar[5]), "v"(ar[6]), "v"(ar[7]),
                "v"(br[0]), "v"(br[1]), "v"(br[2]), "v"(br[3]),
                "v"(br[4]), "v"(br[5]), "v"(br[6]), "v"(br[7]),
                "v"(br[8]), "v"(br[9]), "v"(br[10]), "v"(br[11]));

            #pragma unroll
            for (int q = 0; q < 4; ++q) {
                const f32x4 a0 = ar[2 * q], a1 = ar[2 * q + 1];
                ssq = fmaf(a0[0], a0[0], ssq); ssq = fmaf(a0[1], a0[1], ssq);
                ssq = fmaf(a0[2], a0[2], ssq); ssq = fmaf(a0[3], a0[3], ssq);
                ssq = fmaf(a1[0], a1[0], ssq); ssq = fmaf(a1[1], a1[1], ssq);
                ssq = fmaf(a1[2], a1[2], ssq); ssq = fmaf(a1[3], a1[3], ssq);
                bf16x8 a;
                a[0] = (__bf16)a0[0]; a[1] = (__bf16)a0[1]; a[2] = (__bf16)a0[2]; a[3] = (__bf16)a0[3];
                a[4] = (__bf16)a1[0]; a[5] = (__bf16)a1[1]; a[6] = (__bf16)a1[2]; a[7] = (__bf16)a1[3];
                acc0 = __builtin_amdgcn_mfma_f32_16x16x32_bf16(a, br[3 * q],     acc0, 0, 0, 0);
                acc1 = __builtin_amdgcn_mfma_f32_16x16x32_bf16(a, br[3 * q + 1], acc1, 0, 0, 0);
                acc2 = __builtin_amdgcn_mfma_f32_16x16x32_bf16(a, br[3 * q + 2], acc2, 0, 0, 0);
            }
        }

        ssq += __shfl_xor(ssq, 16, 64);
        ssq += __shfl_xor(ssq, 32, 64);
        if (lane < 16) ssq_red[wv][lane] = ssq;

        // D layout: col=lane&15, row=(lane>>4)*4+reg; row == token 0..15
        #pragma unroll
        for (int rr = 0; rr < 4; ++rr) {
            red[wv][0][g * 4 + rr][r] = acc0[rr];
            red[wv][1][g * 4 + rr][r] = acc1[rr];
            red[wv][2][g * 4 + rr][r] = acc2[rr];
        }
    }
    __syncthreads();   // the only barrier

    // ---------- Phase 3+4 setup: half-wave owns token t ----------
    const int t  = wv * 2 + (lane >> 5);  // wave wv -> tokens 2wv, 2wv+1
    const int l5 = lane & 31;
    const float* src = streams + (tok0 + t) * 4096;
    float* dst = out + (tok0 + t) * 4096;

    // issue first phase-4 load batch NOW; phase-3 math (~250 VALU) hides it
    f32x4 px0 = *reinterpret_cast<const f32x4*>(src + l5 * 4);
    f32x4 px1 = *reinterpret_cast<const f32x4*>(src + 1024 + l5 * 4);
    f32x4 px2 = *reinterpret_cast<const f32x4*>(src + 2048 + l5 * 4);
    f32x4 px3 = *reinterpret_cast<const f32x4*>(src + 3072 + l5 * 4);
    asm volatile("" :: "v"(px0), "v"(px1), "v"(px2), "v"(px3));

    // ---------- Phase 3: build M in registers (redundant per half-wave) ----------
    float Mr[16];
    {
        float st = 0.f;
        #pragma unroll
        for (int kp = 0; kp < 8; ++kp) st += ssq_red[kp][t];
        const float invr = rsqrtf(st * (1.f / 4096.f) + EPS_F);

        #define REDUCE_TILE(tile, raw)                                             \
            {                                                                      \
                _Pragma("unroll")                                                  \
                for (int c4 = 0; c4 < 4; ++c4) {                                   \
                    f32x4 s = {0.f, 0.f, 0.f, 0.f};                                \
                    _Pragma("unroll")                                              \
                    for (int kp = 0; kp < 8; ++kp)                                 \
                        s += *reinterpret_cast<const f32x4*>(&red[kp][tile][t][c4 * 4]); \
                    const float4 pb = *reinterpret_cast<const float4*>(&proj_b[tile * 16 + c4 * 4]); \
                    raw[c4*4 + 0] = s[0] * invr + pb.x;                            \
                    raw[c4*4 + 1] = s[1] * invr + pb.y;                            \
                    raw[c4*4 + 2] = s[2] * invr + pb.z;                            \
                    raw[c4*4 + 3] = s[3] * invr + pb.w;                            \
                }                                                                  \
            }

        float c[4] = {0.f, 0.f, 0.f, 0.f};
        {
            float raw[16];
            REDUCE_TILE(0, raw)
            #pragma unroll
            for (int i = 0; i < 4; ++i) {
                const float a0 = raw[i*4+0], a1 = raw[i*4+1], a2 = raw[i*4+2], a3 = raw[i*4+3];
                const float m = fmaxf(fmaxf(a0, a1), fmaxf(a2, a3));
                const float e0 = expf(a0 - m), e1 = expf(a1 - m);
                const float e2 = expf(a2 - m), e3 = expf(a3 - m);
                const float inv = 1.f / (e0 + e1 + e2 + e3);
                c[0] = fmaf(e0, inv, c[0]); c[1] = fmaf(e1, inv, c[1]);
                c[2] = fmaf(e2, inv, c[2]); c[3] = fmaf(e3, inv, c[3]);
            }
            c[0] *= 0.25f; c[1] *= 0.25f; c[2] *= 0.25f; c[3] *= 0.25f;
        }

        float rs[4] = {0.f, 0.f, 0.f, 0.f};
        {
            float raw[16];
            REDUCE_TILE(1, raw)
            #pragma unroll
            for (int j = 0; j < 4; ++j) {
                const float b0 = raw[j], b1 = raw[4+j], b2 = raw[8+j], b3 = raw[12+j];
                const float m = fmaxf(fmaxf(b0, b1), fmaxf(b2, b3));
                const float e0 = expf(b0 - m), e1 = expf(b1 - m);
                const float e2 = expf(b2 - m), e3 = expf(b3 - m);
                const float inv = 1.f / (e0 + e1 + e2 + e3);
                rs[0] = fmaf(e0, inv, rs[0]); rs[1] = fmaf(e1, inv, rs[1]);
                rs[2] = fmaf(e2, inv, rs[2]); rs[3] = fmaf(e3, inv, rs[3]);
            }
        }

        float W[16], Y[16];
        {
            float raw[16];
            REDUCE_TILE(2, raw)
            #pragma unroll
            for (int i = 0; i < 4; ++i)
                #pragma unroll
                for (int j = 0; j < 4; ++j)
                    W[i*4+j] = raw[i*4+j] - raw[j*4+i];
        }
        #pragma unroll
        for (int i = 0; i < 16; ++i) Y[i] = 0.1f * W[i];
        Y[0] += 1.f; Y[5] += 1.f; Y[10] += 1.f; Y[15] += 1.f;
        #pragma unroll
        for (int it = 0; it < 2; ++it) {
            float T1[16];
            #pragma unroll
            for (int i = 0; i < 16; ++i) T1[i] = Y[i];
            T1[0] += 1.f; T1[5] += 1.f; T1[10] += 1.f; T1[15] += 1.f;
            float Yn[16];
            #pragma unroll
            for (int i = 0; i < 4; ++i)
                #pragma unroll
                for (int j = 0; j < 4; ++j) {
                    float s = W[i*4+0] * T1[0*4+j];
                    s = fmaf(W[i*4+1], T1[1*4+j], s);
                    s = fmaf(W[i*4+2], T1[2*4+j], s);
                    s = fmaf(W[i*4+3], T1[3*4+j], s);
                    Yn[i*4+j] = ((i == j) ? 1.f : 0.f) + 0.05f * s;
                }
            #pragma unroll
            for (int i = 0; i < 16; ++i) Y[i] = Yn[i];
        }

        const float os = out_scale[0];
        #pragma unroll
        for (int i = 0; i < 4; ++i)
            #pragma unroll
            for (int j = 0; j < 4; ++j)
                Mr[i*4+j] = Y[i*4+j] + os * rs[i] * c[j];
        #undef REDUCE_TILE
    }

    // ---------- Phase 4: out[t] = M @ streams[t], cache-hot re-read ----------
    #pragma unroll 2
    for (int cq = 0; cq < 8; ++cq) {
        const f32x4 x0 = px0, x1 = px1, x2 = px2, x3 = px3;
        if (cq < 7) {
            const int ncol = (cq + 1) * 128 + l5 * 4;
            px0 = *reinterpret_cast<const f32x4*>(src + ncol);
            px1 = *reinterpret_cast<const f32x4*>(src + 1024 + ncol);
            px2 = *reinterpret_cast<const f32x4*>(src + 2048 + ncol);
            px3 = *reinterpret_cast<const f32x4*>(src + 3072 + ncol);
        }
        const int col = cq * 128 + l5 * 4;
        #pragma unroll
        for (int i = 0; i < 4; ++i) {
            f32x4 o;
            #pragma unroll
            for (int e = 0; e < 4; ++e)
                o[e] = fmaf(Mr[i*4+3], x3[e],
                        fmaf(Mr[i*4+2], x2[e],
                          fmaf(Mr[i*4+1], x1[e], Mr[i*4+0] * x0[e])));
            __builtin_nontemporal_store(o, reinterpret_cast<f32x4*>(dst + i * 1024 + col));
        }
    }
}

extern "C" void kernel_launch(void* const* d_in, const int* in_sizes, int n_in,
                              void* d_out, int out_size, void* d_ws, size_t ws_size,
                              hipStream_t stream) {
    const float* streams    = (const float*)d_in[0];
    const float* norm_scale = (const float*)d_in[1];
    const float* proj_w     = (const float*)d_in[2];
    const float* proj_b     = (const float*)d_in[3];
    const float* out_scale  = (const float*)d_in[4];
    float* outp = (float*)d_out;

    unsigned int* wbf = (unsigned int*)d_ws;       // 48*4096 bf16 = 393216 B

    scale_weights<<<dim3(192), 256, 0, stream>>>(proj_w, norm_scale, wbf);

    const int n_tok = in_sizes[0] / 4096;          // B*S = 16384
    fused_stream_mix<<<dim3(n_tok / 16), 512, 0, stream>>>(streams,
                                                           (const unsigned short*)wbf,
                                                           proj_b, out_scale, outp);
}